// Round 8
// baseline (5830.667 us; speedup 1.0000x reference)
//
#include <hip/hip_runtime.h>
#include <hip/hip_fp16.h>

typedef unsigned int u32;
typedef unsigned long long u64;
typedef _Float16 half2_t __attribute__((ext_vector_type(2)));
typedef _Float16 f16x8 __attribute__((ext_vector_type(8)));
typedef float f32x16 __attribute__((ext_vector_type(16)));

static constexpr int PL = 300;
static constexpr int QL = 50;
static constexpr int B  = 32;
static constexpr int D  = 256;
static constexpr int H  = 256;

__device__ __forceinline__ float fdot2(u32 w, u32 x, float acc) {
    return __builtin_amdgcn_fdot2(__builtin_bit_cast(half2_t, w),
                                  __builtin_bit_cast(half2_t, x), acc, false);
}
__device__ __forceinline__ u32 packh2(float a, float b) {
    half2_t h2; h2[0] = (_Float16)a; h2[1] = (_Float16)b;
    return __builtin_bit_cast(u32, h2);
}
__device__ __forceinline__ f32x16 mfma16(uint4 a, uint4 b, f32x16 c) {
    return __builtin_amdgcn_mfma_f32_32x32x16_f16(
        __builtin_bit_cast(f16x8, a), __builtin_bit_cast(f16x8, b), c, 0, 0, 0);
}
__device__ __forceinline__ u64 a_ld64(const u64* p) {
    return __hip_atomic_load(p, __ATOMIC_RELAXED, __HIP_MEMORY_SCOPE_AGENT);
}
__device__ __forceinline__ void a_st64(u64* p, u64 v) {
    __hip_atomic_store(p, v, __ATOMIC_RELAXED, __HIP_MEMORY_SCOPE_AGENT);
}
// spin until word's hi32 == want; return lo32 payload
__device__ __forceinline__ u32 spin_word(const u64* p, u32 want) {
    u64 w = a_ld64(p);
    while ((u32)(w >> 32) != want) {
        __builtin_amdgcn_s_sleep(1);
        w = a_ld64(p);
    }
    return (u32)w;
}

// ---- pack MFMA weight tile per (dd,j): rows 0..31 = gate rows (Wih*gamma | Whh),
// ---- rows 32..39 = Wr rows 8j..8j+7 in h-octets. Linear; swizzle applied at LDS stage.
__global__ __launch_bounds__(256) void pack_wt(const float* __restrict__ Wih,
                                               const float* __restrict__ Whh,
                                               const float* __restrict__ Wr,
                                               const float* __restrict__ lng,
                                               u32* __restrict__ dst) {
    int id = blockIdx.x * 256 + threadIdx.x;    // < 655360
    int u = id & 255;
    int rw = (id >> 8) % 40;
    int j  = ((id >> 8) / 40) % 32;
    int dd = (id >> 8) / 1280;
    float a = 0.f, c = 0.f;
    if (rw < 32) {
        int R = (rw >> 3) * 256 + 8 * j + (rw & 7);
        if (u < 128) {
            int k = 2 * u;
            a = Wih[((size_t)dd * 1024 + R) * 512 + k]     * lng[dd * 512 + k];
            c = Wih[((size_t)dd * 1024 + R) * 512 + k + 1] * lng[dd * 512 + k + 1];
        } else {
            int k = 2 * (u - 128);
            a = Whh[((size_t)dd * 1024 + R) * 256 + k];
            c = Whh[((size_t)dd * 1024 + R) * 256 + k + 1];
        }
    } else if (u >= 128) {
        int k = 2 * (u - 128);
        int wrr = 8 * j + (rw - 32);
        a = Wr[((size_t)dd * 256 + wrr) * 256 + k];
        c = Wr[((size_t)dd * 256 + wrr) * 256 + k + 1];
    }
    dst[id] = packh2(a, c);
}

// ---- prep: out[g][b][t][h] = bias[g][h] + sum_d X[t][b][d]*W[g][h][d] ----
__global__ __launch_bounds__(256) void prep_proj(const float* __restrict__ X,
                                                 const float* __restrict__ W,
                                                 const float* __restrict__ Bv,
                                                 __half* __restrict__ out,
                                                 int T, int nt) {
    int id = blockIdx.x;
    int tb = id % nt; id /= nt;
    int b  = id % B;  id /= B;
    int g  = id;
    int t0 = tb * 8;
    int nr = T - t0; if (nr > 8) nr = 8;
    __shared__ __align__(16) float xs[8][256];
    int tid = threadIdx.x;
    for (int r = 0; r < nr; r++) xs[r][tid] = X[((t0 + r) * B + b) * D + tid];
    __syncthreads();
    const float4* wrow = (const float4*)&W[(g * H + tid) * D];
    float bb = Bv[g * H + tid];
    float acc[8];
#pragma unroll
    for (int r = 0; r < 8; r++) acc[r] = bb;
    for (int d4 = 0; d4 < D / 4; d4++) {
        float4 w = wrow[d4];
#pragma unroll
        for (int r = 0; r < 8; r++) {
            float4 x = *(const float4*)&xs[r][d4 * 4];
            acc[r] = fmaf(w.x, x.x, fmaf(w.y, x.y, fmaf(w.z, x.z, fmaf(w.w, x.w, acc[r]))));
        }
    }
    for (int r = 0; r < nr; r++)
        out[((g * B + b) * T + t0 + r) * H + tid] = __float2half(acc[r]);
}

// ---- VP[dd][b][r][56 q] f16 = sum_k Wih[dd][r][256+k]*lng[dd][256+k]*qv[q][b][k] ----
__global__ __launch_bounds__(256) void vp_prep(const float* __restrict__ qv,
                                               const float* __restrict__ Wih,
                                               const float* __restrict__ lng,
                                               __half* __restrict__ VP) {
    int blk = blockIdx.x;               // 512
    int dd = blk >> 8, b = (blk >> 3) & 31, rc = blk & 7;
    __shared__ __align__(16) u32 qg[50 * 128];
    __shared__ __align__(16) u32 wch[128 * 128];
    int tid = threadIdx.x;
    for (int v = tid; v < 6400; v += 256) {
        int q = v >> 7, i = v & 127;
        float a = qv[((size_t)q * 32 + b) * 256 + 2 * i]     * lng[dd * 512 + 256 + 2 * i];
        float c = qv[((size_t)q * 32 + b) * 256 + 2 * i + 1] * lng[dd * 512 + 256 + 2 * i + 1];
        qg[v] = packh2(a, c);
    }
    for (int v = tid; v < 16384; v += 256) {
        int rl = v >> 7, i = v & 127;
        int r = rc * 128 + rl;
        float a = Wih[((size_t)dd * 1024 + r) * 512 + 256 + 2 * i];
        float c = Wih[((size_t)dd * 1024 + r) * 512 + 256 + 2 * i + 1];
        wch[v] = packh2(a, c);
    }
    __syncthreads();
    for (int p = tid; p < 128 * 56; p += 256) {
        int rl = p / 56, q = p % 56;
        int r = rc * 128 + rl;
        float acc = 0.f;
        if (q < 50) {
            const u32* qr = qg + q * 128;
            const u32* wr = wch + rl * 128;
#pragma unroll 8
            for (int i = 0; i < 128; i++) acc = fdot2(wr[i], qr[i], acc);
        }
        VP[((size_t)(dd * 32 + b) * 1024 + r) * 56 + q] = __float2half(acc);
    }
}

// ---- Gram G[b][50][50], rowsums qs[b][52] ----
__global__ __launch_bounds__(256) void gram_prep(const float* __restrict__ qv,
                                                 float* __restrict__ G,
                                                 float* __restrict__ qs) {
    int b = blockIdx.x;
    __shared__ float qvs[50 * 256];
    int tid = threadIdx.x;
    for (int v = tid; v < 12800; v += 256) {
        int q = v >> 8, k = v & 255;
        qvs[v] = qv[((size_t)q * 32 + b) * 256 + k];
    }
    __syncthreads();
    for (int p = tid; p < 2500; p += 256) {
        int q = p / 50, q2 = p % 50;
        float acc = 0.f;
        for (int k = 0; k < 256; k++) acc = fmaf(qvs[q * 256 + k], qvs[q2 * 256 + k], acc);
        G[((size_t)b * 50 + q) * 50 + q2] = acc;
    }
    if (tid < 52) {
        float s = 0.f;
        if (tid < 50) for (int k = 0; k < 256; k++) s += qvs[tid * 256 + k];
        qs[b * 52 + tid] = s;
    }
}

// ---- cvstats[b][t][2] = {sum, sumsq} over cv[t,b,:] ----
__global__ __launch_bounds__(256) void cvstats_prep(const float* __restrict__ cv,
                                                    float* __restrict__ st) {
    int blk = blockIdx.x;               // 9600
    int t = blk >> 5, b = blk & 31;
    int tid = threadIdx.x;
    float v = cv[((size_t)t * 32 + b) * 256 + tid];
    float s = v, s2 = v * v;
#pragma unroll
    for (int m = 32; m; m >>= 1) { s += __shfl_xor(s, m, 64); s2 += __shfl_xor(s2, m, 64); }
    __shared__ float red[8];
    if ((tid & 63) == 0) { red[(tid >> 6) * 2] = s; red[(tid >> 6) * 2 + 1] = s2; }
    __syncthreads();
    if (tid == 0) {
        float S = red[0] + red[2] + red[4] + red[6];
        float S2 = red[1] + red[3] + red[5] + red[7];
        st[((size_t)b * 300 + t) * 2] = S;
        st[((size_t)b * 300 + t) * 2 + 1] = S2;
    }
}

// ---- C12[dd][R][2] = {sum_k W[R,k]*gamma[k], sum_k W[R,k]*beta[k] + bih + bhh} ----
__global__ __launch_bounds__(256) void c1c2_prep(const float* __restrict__ Wih,
                                                 const float* __restrict__ lng,
                                                 const float* __restrict__ lnb,
                                                 const float* __restrict__ bih,
                                                 const float* __restrict__ bhh,
                                                 float* __restrict__ C12) {
    int id = blockIdx.x * 256 + threadIdx.x;    // < 2048
    int dd = id >> 10, R = id & 1023;
    float s1 = 0.f, s2 = 0.f;
    const float* wr = &Wih[((size_t)dd * 1024 + R) * 512];
    for (int k = 0; k < 512; k++) {
        float w = wr[k];
        s1 = fmaf(w, lng[dd * 512 + k], s1);
        s2 = fmaf(w, lnb[dd * 512 + k], s2);
    }
    C12[(size_t)id * 2] = s1;
    C12[(size_t)id * 2 + 1] = s2 + bih[dd * 1024 + R] + bhh[dd * 1024 + R];
}

// ================= main scan: 64 blocks; seq-embedded u64 exchange (tag = data) =================
__global__ __launch_bounds__(256, 1) void scan8(
    const float* __restrict__ cv,       // [300][32][256]
    const int*   __restrict__ cmask,    // [32][300]
    const int*   __restrict__ qmask,    // [32][50]
    const float* __restrict__ Wgv,      // [2][256]
    const float* __restrict__ bgv,      // [2]
    const float* __restrict__ brp,      // [2][256]
    const u32*   __restrict__ Wtp,      // [2*32][40][256]
    const __half* __restrict__ whp,     // [2][32][50][256]
    const __half* __restrict__ hpp,     // [2][32][300][256]
    const __half* __restrict__ VP,      // [2*32][1024][56]
    const float* __restrict__ C12,      // [2][1024][2]
    const float* __restrict__ G,        // [32][50][50]
    const float* __restrict__ qsr,      // [32][52]
    const float* __restrict__ cvst,     // [32][300][2]
    u64* __restrict__ HX,               // [2*32][128]  seq|2half
    u64* __restrict__ B1X,              // [2*32][1024] seq|f32
    u64* __restrict__ B2X,              // [2*32][1024] seq|f32
    u64* __restrict__ B3X,              // [2*32][256]  seq|f32
    float* __restrict__ out)            // [300][32][512]
{
    int blk = blockIdx.x;
    int dd = blk >> 5, j = blk & 31;
    int tid = threadIdx.x;
    int lane = tid & 63, wave = tid >> 6;
    int rr = lane & 31, kh = lane >> 5, sw = rr & 7;

    __shared__ __align__(16) u32 sh_wt[40 * 256];
    __shared__ __align__(16) u32 sh_x[32 * 256];
    __shared__ __align__(16) u32 sh_wh[6400];
    __shared__ float sh_G[50 * 50];
    __shared__ float sh_red1[2 * 32 * 33];
    __shared__ float sh_red2[2 * 32 * 33];
    __shared__ float sh_red3[4 * 32 * 8];
    __shared__ float sh_C1[1024];
    __shared__ float sh_C2[1024];
    __shared__ float sh_a[256];
    __shared__ float sh_qs[52];
    __shared__ float sh_af[64];
    __shared__ __align__(16) u32 sh_al2[28];
    __shared__ float sh_alpha[64];
    __shared__ float sh_qb[64];
    __shared__ float sh_r2[4];
    __shared__ float sh_cs[2];
    __shared__ int   sh_len[32];

    // ---------- one-time staging ----------
    for (int v = tid; v < 40 * 256; v += 256) {
        int rl = v >> 8, u = v & 255;
        int c4 = u >> 2, w = u & 3;
        sh_wt[rl * 256 + (((c4 ^ (rl & 7)) << 2) | w)] =
            Wtp[((size_t)(dd * 32 + j) * 40 + rl) * 256 + u];
    }
    {
        const u32* whsrc = (const u32*)(whp + (size_t)(dd * 32 + j) * QL * H);
        for (int i = tid; i < 6400; i += 256) sh_wh[i] = whsrc[i];
    }
    for (int v = tid; v < 2500; v += 256) sh_G[v] = G[(size_t)j * 2500 + v];
    if (tid < 52) sh_qs[tid] = qsr[j * 52 + tid];
    for (int v = tid; v < 1024; v += 256) {
        sh_C1[v] = C12[((size_t)dd * 1024 + v) * 2];
        sh_C2[v] = C12[((size_t)dd * 1024 + v) * 2 + 1];
    }
    if (tid < 64) sh_qb[tid] = (tid < QL) ? (qmask[j * QL + tid] ? 0.f : -1e30f) : -1e30f;
    if (tid < 32) sh_len[tid] = 0;
    __syncthreads();
    {
        int b = tid & 31, part = tid >> 5;
        int t0 = part * 38, t1 = t0 + 38 > PL ? PL : t0 + 38;
        int s = 0;
        for (int tt = t0; tt < t1; tt++) s += cmask[b * PL + tt];
        atomicAdd(&sh_len[b], s);
    }
    __syncthreads();

    float wgr[4];
#pragma unroll
    for (int i = 0; i < 4; i++) wgr[i] = Wgv[dd * H + lane + 64 * i];
    float bgs = bgv[dd];
    float brv = brp[dd * H + tid];
    int len_j = sh_len[j];
    float c_reg = 0.f;

    // zero own-batch masked tail (own 256-col half-row)
    for (int t = len_j; t < PL; t++)
        out[((size_t)t * B + j) * 512 + dd * 256 + tid] = 0.f;

    // prologue: publish h(0)=0 with seq 1
    if (tid < 128) a_st64(HX + (size_t)(dd * 32 + j) * 128 + tid, ((u64)1 << 32));

    const __half* hpb = hpp + (size_t)(dd * 32 + j) * PL * H;
    const u32* VPu = (const u32*)VP;
    const u32* xrow  = sh_x + rr * 256;
    const u32* wrow  = sh_wt + rr * 256;
    const u32* wrow2 = sh_wt + (8 + rr) * 256;

    for (int t = 0; t < PL; t++) {
        u32 want = (u32)(t + 1);
        int tsj = dd ? (t < len_j ? len_j - 1 - t : t) : t;
        __syncthreads();   // protect sh_cs / sh_x from prev-step stragglers

        // ---- A: cv stage (swizzled f16), own hp + cvstats ----
        {
            int b = tid >> 3, sub = tid & 7;
            int lenb = sh_len[b];
            int tsb = dd ? (t < lenb ? lenb - 1 - t : t) : t;
            const float4* src = (const float4*)(cv + ((size_t)tsb * 32 + b) * 256 + sub * 32);
#pragma unroll
            for (int i = 0; i < 4; i++) {
                float4 e = src[2 * i], o = src[2 * i + 1];
                uint4 pk = { packh2(e.x, e.y), packh2(e.z, e.w),
                             packh2(o.x, o.y), packh2(o.z, o.w) };
                int c4 = sub * 4 + i;
                *(uint4*)(sh_x + b * 256 + ((c4 ^ (b & 7)) << 2)) = pk;
            }
        }
        float hpv = __half2float(hpb[(size_t)tsj * H + tid]);
        if (tid == 0) {
            sh_cs[0] = cvst[((size_t)j * 300 + tsj) * 2];
            sh_cs[1] = cvst[((size_t)j * 300 + tsj) * 2 + 1];
        }

        // ---- B: h poll + stage fused (16 words/thread; payload = 2 halfs) ----
#pragma unroll
        for (int m = 0; m < 16; m++) {
            int f = m * 256 + tid;
            int b = f >> 7, c2 = f & 127;
            u32 pay = spin_word(HX + (size_t)(dd * 32 + b) * 128 + c2, want);
            int oct = 32 + (c2 >> 2);
            sh_x[b * 256 + (((oct ^ (b & 7)) << 2) | (c2 & 3))] = pay;
        }
        __syncthreads();

        // ---- C: MFMA. acc1: gate rows (B1 waves 0,1 / B2 waves 2,3); acc2: Wr rows ----
        {
            f32x16 acc1 = {}, acc2 = {};
#pragma unroll
            for (int kk = 0; kk < 8; kk++) {
                int c4 = wave * 16 + 2 * kk + kh;
                int pc4 = (c4 ^ sw) << 2;
                uint4 au = *(const uint4*)(xrow + pc4);
                uint4 bu = *(const uint4*)(wrow + pc4);
                acc1 = mfma16(au, bu, acc1);
            }
#pragma unroll
            for (int kk = 0; kk < 4; kk++) {
                int c4 = 32 + wave * 8 + 2 * kk + kh;
                int pc4 = (c4 ^ sw) << 2;
                uint4 au = *(const uint4*)(xrow + pc4);
                uint4 bu = *(const uint4*)(wrow2 + pc4);
                acc2 = mfma16(au, bu, acc2);
            }
            float* dstP = (wave < 2) ? &sh_red1[wave * 32 * 33] : &sh_red2[(wave - 2) * 32 * 33];
#pragma unroll
            for (int q = 0; q < 16; q++) {
                int b = (q & 3) + 8 * (q >> 2) + 4 * kh;
                dstP[b * 33 + rr] = acc1[q];
            }
            if (rr >= 24) {
#pragma unroll
                for (int q = 0; q < 16; q++) {
                    int b = (q & 3) + 8 * (q >> 2) + 4 * kh;
                    sh_red3[(wave * 32 + b) * 8 + (rr - 24)] = acc2[q];
                }
            }
        }
        __syncthreads();

        // ---- D: reduce + publish B1/B2/B3 as seq|f32 words (no drain, no tag) ----
        {
            int b = tid >> 3, rq = (tid & 7) * 4;
            u64 sq = ((u64)want) << 32;
            size_t base = (size_t)(dd * 32 + b) * 1024 + j * 32 + rq;
#pragma unroll
            for (int i = 0; i < 4; i++) {
                float f1 = sh_red1[b * 33 + rq + i] + sh_red1[1056 + b * 33 + rq + i];
                float f2 = sh_red2[b * 33 + rq + i] + sh_red2[1056 + b * 33 + rq + i];
                a_st64(B1X + base + i, sq | (u64)__builtin_bit_cast(u32, f1));
                a_st64(B2X + base + i, sq | (u64)__builtin_bit_cast(u32, f2));
            }
            int rw = tid & 7;
            float b3 = sh_red3[b * 8 + rw] + sh_red3[(32 + b) * 8 + rw]
                     + sh_red3[(64 + b) * 8 + rw] + sh_red3[(96 + b) * 8 + rw];
            a_st64(B3X + (size_t)(dd * 32 + b) * 256 + 8 * j + rw,
                   sq | (u64)__builtin_bit_cast(u32, b3));
        }

        // ---- E: issue VP loads (own-batch alpha-VP weights) ----
        uint4 vp[28];
#pragma unroll
        for (int k = 0; k < 4; k++) {
            const uint4* vr = (const uint4*)(VPu + ((size_t)(dd * 32 + j) * 1024 + k * 256 + tid) * 28);
#pragma unroll
            for (int i = 0; i < 7; i++) vp[k * 7 + i] = vr[i];
        }

        // ---- F: poll own-batch B words (9 per thread) ----
        float bg1[4], bg2[4];
        {
            size_t bb = (size_t)(dd * 32 + j) * 1024 + (tid >> 3) * 32 + (tid & 7);
#pragma unroll
            for (int k = 0; k < 4; k++) {
                bg1[k] = __builtin_bit_cast(float, spin_word(B1X + bb + k * 8, want));
                bg2[k] = __builtin_bit_cast(float, spin_word(B2X + bb + k * 8, want));
            }
            float hrv = __builtin_bit_cast(float,
                spin_word(B3X + (size_t)(dd * 32 + j) * 256 + tid, want));
            sh_a[tid] = hrv + brv + hpv;
        }
        __syncthreads();

        // ---- G: attention logits + softmax ----
        {
            float av[4];
#pragma unroll
            for (int i = 0; i < 4; i++) av[i] = sh_a[lane + 64 * i];
            const __half* wh16 = (const __half*)sh_wh;
            for (int q = wave; q < QL; q += 4) {
                float a = 0.f;
#pragma unroll
                for (int i = 0; i < 4; i++) {
                    float xx = (float)wh16[q * 256 + lane + 64 * i] + av[i];
                    float e = __expf(2.f * xx);
                    a = fmaf(wgr[i], (e - 1.f) / (e + 1.f), a);
                }
#pragma unroll
                for (int m = 32; m; m >>= 1) a += __shfl_xor(a, m, 64);
                if (lane == 0) sh_alpha[q] = a + bgs + sh_qb[q];
            }
        }
        __syncthreads();
        if (wave == 0) {
            float v = (lane < QL) ? sh_alpha[lane] : -1e30f;
            float m = v;
#pragma unroll
            for (int s = 32; s; s >>= 1) m = fmaxf(m, __shfl_xor(m, s, 64));
            float e = (lane < QL) ? __expf(v - m) : 0.f;
            float sum = e;
#pragma unroll
            for (int s = 32; s; s >>= 1) sum += __shfl_xor(sum, s, 64);
            float al = (lane < QL) ? e / sum : 0.f;
            sh_af[lane] = al;
            float alo = __shfl_xor(al, 1, 64);
            if (!(lane & 1) && lane < 56) sh_al2[lane >> 1] = packh2(al, alo);
        }
        __syncthreads();

        // ---- H: stats mu, rs from Gram ----
        if (wave == 0) {
            float gd = 0.f;
            if (lane < QL) {
                const float* Grow = sh_G + lane * 50;
                float aq = sh_af[lane];
                for (int q2 = 0; q2 < QL; q2++) gd = fmaf(Grow[q2], sh_af[q2], gd);
                gd *= aq;
            }
#pragma unroll
            for (int m = 32; m; m >>= 1) gd += __shfl_xor(gd, m, 64);
            if (lane == 0) sh_r2[0] = gd;
        } else if (wave == 1) {
            float s = (lane < QL) ? sh_af[lane] * sh_qs[lane] : 0.f;
#pragma unroll
            for (int m = 32; m; m >>= 1) s += __shfl_xor(s, m, 64);
            if (lane == 0) sh_r2[1] = s;
        }
        __syncthreads();

        // ---- I: alpha . VP ----
        float aVP[4];
#pragma unroll
        for (int k = 0; k < 4; k++) {
            float acc = 0.f;
#pragma unroll
            for (int i = 0; i < 7; i++) {
                acc = fdot2(vp[k * 7 + i].x, sh_al2[i * 4 + 0], acc);
                acc = fdot2(vp[k * 7 + i].y, sh_al2[i * 4 + 1], acc);
                acc = fdot2(vp[k * 7 + i].z, sh_al2[i * 4 + 2], acc);
                acc = fdot2(vp[k * 7 + i].w, sh_al2[i * 4 + 3], acc);
            }
            aVP[k] = acc;
        }

        // ---- J: assemble gates + LSTM pointwise + publish h(t+1) ----
        float hv;
        {
            float mu = (sh_cs[0] + sh_r2[1]) * (1.f / 512.f);
            float E2 = (sh_cs[1] + sh_r2[0]) * (1.f / 512.f);
            float rs = rsqrtf(E2 - mu * mu + 1e-5f);
            float gk[4];
#pragma unroll
            for (int k = 0; k < 4; k++)
                gk[k] = rs * (bg1[k] + aVP[k]) - rs * mu * sh_C1[k * 256 + tid]
                      + sh_C2[k * 256 + tid] + bg2[k];
            float si = 1.f / (1.f + __expf(-gk[0]));
            float sf = 1.f / (1.f + __expf(-gk[1]));
            float so = 1.f / (1.f + __expf(-gk[3]));
            float eg = __expf(2.f * gk[2]); float tg = (eg - 1.f) / (eg + 1.f);
            float c = sf * c_reg + si * tg;
            float ec = __expf(2.f * c); float tc = (ec - 1.f) / (ec + 1.f);
            hv = so * tc;
            c_reg = c;
            float ho = __shfl_xor(hv, 1, 64);
            if (!(tid & 1))
                a_st64(HX + (size_t)(dd * 32 + j) * 128 + (tid >> 1),
                       (((u64)(t + 2)) << 32) | (u64)packh2(hv, ho));
        }

        // ---- K: output store (off critical path) ----
        if (t < len_j)
            out[((size_t)tsj * B + j) * 512 + dd * 256 + tid] = hv;
    }
}

extern "C" void kernel_launch(void* const* d_in, const int* in_sizes, int n_in,
                              void* d_out, int out_size, void* d_ws, size_t ws_size,
                              hipStream_t stream) {
    const float* cv    = (const float*)d_in[0];
    const int*   cmask = (const int*)  d_in[1];
    const float* qv    = (const float*)d_in[2];
    const int*   qmask = (const int*)  d_in[3];
    const float* Wq    = (const float*)d_in[4];
    const float* bq    = (const float*)d_in[5];
    const float* Wp    = (const float*)d_in[6];
    const float* bp    = (const float*)d_in[7];
    const float* Wr    = (const float*)d_in[8];
    const float* br    = (const float*)d_in[9];
    const float* Wg    = (const float*)d_in[10];
    const float* bg    = (const float*)d_in[11];
    const float* ln_g  = (const float*)d_in[12];
    const float* ln_b  = (const float*)d_in[13];
    const float* Wih   = (const float*)d_in[14];
    const float* Whh   = (const float*)d_in[15];
    const float* b_ih  = (const float*)d_in[16];
    const float* b_hh  = (const float*)d_in[17];
    float* out = (float*)d_out;

    uint8_t* ws = (uint8_t*)d_ws;
    u32*    Wtp = (u32*)ws;      ws += (size_t)2 * 32 * 40 * 256 * 4;   // 2.62 MB
    __half* VP  = (__half*)ws;   ws += (size_t)2 * 32 * 1024 * 56 * 2;  // 7.34 MB
    __half* whp = (__half*)ws;   ws += (size_t)2 * 32 * 50 * 256 * 2;   // 1.64 MB
    __half* hpp = (__half*)ws;   ws += (size_t)2 * 32 * 300 * 256 * 2;  // 9.83 MB
    float*  C12 = (float*)ws;    ws += (size_t)2 * 1024 * 2 * 4;        // 16 KB
    float*  G   = (float*)ws;    ws += (size_t)32 * 50 * 50 * 4;        // 320 KB
    float*  qs  = (float*)ws;    ws += (size_t)32 * 52 * 4;             // 6.7 KB
    float*  cvs = (float*)ws;    ws += (size_t)32 * 300 * 2 * 4;        // 77 KB
    u64* HX  = (u64*)ws;         ws += (size_t)2 * 32 * 128 * 8;        // 64 KB
    u64* B1X = (u64*)ws;         ws += (size_t)2 * 32 * 1024 * 8;       // 512 KB
    u64* B2X = (u64*)ws;         ws += (size_t)2 * 32 * 1024 * 8;       // 512 KB
    u64* B3X = (u64*)ws;         ws += (size_t)2 * 32 * 256 * 8;        // 128 KB

    hipMemsetAsync(HX, 0, (size_t)(2 * 32 * 128 + 2 * 2 * 32 * 1024 + 2 * 32 * 256) * 8,
                   stream);
    hipLaunchKernelGGL(pack_wt, dim3(2560), dim3(256), 0, stream, Wih, Whh, Wr, ln_g, Wtp);
    hipLaunchKernelGGL(prep_proj, dim3(2 * 32 * 7), dim3(256), 0, stream,
                       qv, Wq, bq, whp, QL, 7);
    hipLaunchKernelGGL(prep_proj, dim3(2 * 32 * 38), dim3(256), 0, stream,
                       cv, Wp, bp, hpp, PL, 38);
    hipLaunchKernelGGL(vp_prep, dim3(512), dim3(256), 0, stream, qv, Wih, ln_g, VP);
    hipLaunchKernelGGL(gram_prep, dim3(32), dim3(256), 0, stream, qv, G, qs);
    hipLaunchKernelGGL(cvstats_prep, dim3(9600), dim3(256), 0, stream, cv, cvs);
    hipLaunchKernelGGL(c1c2_prep, dim3(8), dim3(256), 0, stream,
                       Wih, ln_g, ln_b, b_ih, b_hh, C12);
    hipLaunchKernelGGL(scan8, dim3(64), dim3(256), 0, stream,
                       cv, cmask, qmask, Wg, bg, br, Wtp, whp, hpp, VP, C12, G, qs, cvs,
                       HX, B1X, B2X, B3X, out);
}

// Round 10
// 4026.225 us; speedup vs baseline: 1.4482x; 1.4482x over previous
//
#include <hip/hip_runtime.h>
#include <hip/hip_fp16.h>

typedef unsigned int u32;
typedef unsigned long long u64;
typedef _Float16 half2_t __attribute__((ext_vector_type(2)));
typedef _Float16 f16x8 __attribute__((ext_vector_type(8)));
typedef float f32x16 __attribute__((ext_vector_type(16)));

static constexpr int PL = 300;
static constexpr int QL = 50;
static constexpr int B  = 32;
static constexpr int D  = 256;
static constexpr int H  = 256;

__device__ __forceinline__ float fdot2(u32 w, u32 x, float acc) {
    return __builtin_amdgcn_fdot2(__builtin_bit_cast(half2_t, w),
                                  __builtin_bit_cast(half2_t, x), acc, false);
}
__device__ __forceinline__ u32 packh2(float a, float b) {
    half2_t h2; h2[0] = (_Float16)a; h2[1] = (_Float16)b;
    return __builtin_bit_cast(u32, h2);
}
__device__ __forceinline__ f32x16 mfma16(uint4 a, uint4 b, f32x16 c) {
    return __builtin_amdgcn_mfma_f32_32x32x16_f16(
        __builtin_bit_cast(f16x8, a), __builtin_bit_cast(f16x8, b), c, 0, 0, 0);
}
__device__ __forceinline__ u32 a_ld32(const u32* p) {
    return __hip_atomic_load(p, __ATOMIC_RELAXED, __HIP_MEMORY_SCOPE_AGENT);
}
__device__ __forceinline__ u64 a_ld64(const u64* p) {
    return __hip_atomic_load(p, __ATOMIC_RELAXED, __HIP_MEMORY_SCOPE_AGENT);
}
__device__ __forceinline__ void a_st32(u32* p, u32 v) {
    __hip_atomic_store(p, v, __ATOMIC_RELAXED, __HIP_MEMORY_SCOPE_AGENT);
}
__device__ __forceinline__ void a_st64(u64* p, u64 v) {
    __hip_atomic_store(p, v, __ATOMIC_RELAXED, __HIP_MEMORY_SCOPE_AGENT);
}

// ---- pack MFMA weight tile per (dd,j): rows 0..31 = Whh gate rows, rows 32..39 = Wr rows ----
__global__ __launch_bounds__(256) void pack_wt2(const float* __restrict__ Whh,
                                                const float* __restrict__ Wr,
                                                u32* __restrict__ dst) {
    int id = blockIdx.x * 256 + threadIdx.x;    // < 327680
    int u  = id & 127;
    int rw = (id >> 7) % 40;
    int j  = ((id >> 7) / 40) % 32;
    int dd = (id >> 7) / 1280;
    float a, c;
    if (rw < 32) {
        int R = (rw >> 3) * 256 + 8 * j + (rw & 7);
        a = Whh[((size_t)dd * 1024 + R) * 256 + 2 * u];
        c = Whh[((size_t)dd * 1024 + R) * 256 + 2 * u + 1];
    } else {
        int wrr = 8 * j + (rw - 32);
        a = Wr[((size_t)dd * 256 + wrr) * 256 + 2 * u];
        c = Wr[((size_t)dd * 256 + wrr) * 256 + 2 * u + 1];
    }
    dst[id] = packh2(a, c);
}

// ---- prep: out[g][b][t][h] = bias[g][h] + sum_d X[t][b][d]*W[g][h][d] ----
__global__ __launch_bounds__(256) void prep_proj(const float* __restrict__ X,
                                                 const float* __restrict__ W,
                                                 const float* __restrict__ Bv,
                                                 __half* __restrict__ out,
                                                 int T, int nt) {
    int id = blockIdx.x;
    int tb = id % nt; id /= nt;
    int b  = id % B;  id /= B;
    int g  = id;
    int t0 = tb * 8;
    int nr = T - t0; if (nr > 8) nr = 8;
    __shared__ __align__(16) float xs[8][256];
    int tid = threadIdx.x;
    for (int r = 0; r < nr; r++) xs[r][tid] = X[((t0 + r) * B + b) * D + tid];
    __syncthreads();
    const float4* wrow = (const float4*)&W[(g * H + tid) * D];
    float bb = Bv[g * H + tid];
    float acc[8];
#pragma unroll
    for (int r = 0; r < 8; r++) acc[r] = bb;
    for (int d4 = 0; d4 < D / 4; d4++) {
        float4 w = wrow[d4];
#pragma unroll
        for (int r = 0; r < 8; r++) {
            float4 x = *(const float4*)&xs[r][d4 * 4];
            acc[r] = fmaf(w.x, x.x, fmaf(w.y, x.y, fmaf(w.z, x.z, fmaf(w.w, x.w, acc[r]))));
        }
    }
    for (int r = 0; r < nr; r++)
        out[((g * B + b) * T + t0 + r) * H + tid] = __float2half(acc[r]);
}

// ---- P1[dd][b][t][1024] f16 = sum_{k<256} Wih[dd][R][k]*lng[dd][k]*cv[t][b][k] ----
__global__ __launch_bounds__(256) void p1_prep(const float* __restrict__ cv,
                                               const float* __restrict__ Wih,
                                               const float* __restrict__ lng,
                                               __half* __restrict__ P1) {
    int id = blockIdx.x;           // 2*32*38
    int tb = id % 38; id /= 38;
    int b  = id % 32; id /= 32;
    int dd = id;
    int t0 = tb * 8;
    int nr = PL - t0; if (nr > 8) nr = 8;
    __shared__ __align__(16) float xs[8][256];
    int tid = threadIdx.x;
    float g = lng[dd * 512 + tid];
    for (int r = 0; r < nr; r++)
        xs[r][tid] = cv[((size_t)(t0 + r) * B + b) * D + tid] * g;
    __syncthreads();
    for (int gc = 0; gc < 4; gc++) {
        int R = gc * 256 + tid;
        const float4* wrow = (const float4*)&Wih[((size_t)dd * 1024 + R) * 512];
        float acc[8] = {};
        for (int d4 = 0; d4 < 64; d4++) {
            float4 w = wrow[d4];
#pragma unroll
            for (int r = 0; r < 8; r++) {
                float4 x = *(const float4*)&xs[r][d4 * 4];
                acc[r] = fmaf(w.x, x.x, fmaf(w.y, x.y, fmaf(w.z, x.z, fmaf(w.w, x.w, acc[r]))));
            }
        }
        for (int r = 0; r < nr; r++)
            P1[((size_t)(dd * 32 + b) * PL + t0 + r) * 1024 + R] = __float2half(acc[r]);
    }
}

// ---- VP[dd][b][r][56 q] f16 = sum_k Wih[dd][r][256+k]*lng[dd][256+k]*qv[q][b][k] ----
__global__ __launch_bounds__(256) void vp_prep(const float* __restrict__ qv,
                                               const float* __restrict__ Wih,
                                               const float* __restrict__ lng,
                                               __half* __restrict__ VP) {
    int blk = blockIdx.x;               // 512
    int dd = blk >> 8, b = (blk >> 3) & 31, rc = blk & 7;
    __shared__ __align__(16) u32 qg[50 * 128];
    __shared__ __align__(16) u32 wch[128 * 128];
    int tid = threadIdx.x;
    for (int v = tid; v < 6400; v += 256) {
        int q = v >> 7, i = v & 127;
        float a = qv[((size_t)q * 32 + b) * 256 + 2 * i]     * lng[dd * 512 + 256 + 2 * i];
        float c = qv[((size_t)q * 32 + b) * 256 + 2 * i + 1] * lng[dd * 512 + 256 + 2 * i + 1];
        qg[v] = packh2(a, c);
    }
    for (int v = tid; v < 16384; v += 256) {
        int rl = v >> 7, i = v & 127;
        int r = rc * 128 + rl;
        float a = Wih[((size_t)dd * 1024 + r) * 512 + 256 + 2 * i];
        float c = Wih[((size_t)dd * 1024 + r) * 512 + 256 + 2 * i + 1];
        wch[v] = packh2(a, c);
    }
    __syncthreads();
    for (int p = tid; p < 128 * 56; p += 256) {
        int rl = p / 56, q = p % 56;
        int r = rc * 128 + rl;
        float acc = 0.f;
        if (q < 50) {
            const u32* qr = qg + q * 128;
            const u32* wr = wch + rl * 128;
#pragma unroll 8
            for (int i = 0; i < 128; i++) acc = fdot2(wr[i], qr[i], acc);
        }
        VP[((size_t)(dd * 32 + b) * 1024 + r) * 56 + q] = __float2half(acc);
    }
}

// ---- Gram G[b][50][50], rowsums qs[b][52] ----
__global__ __launch_bounds__(256) void gram_prep(const float* __restrict__ qv,
                                                 float* __restrict__ G,
                                                 float* __restrict__ qs) {
    int b = blockIdx.x;
    __shared__ float qvs[50 * 256];
    int tid = threadIdx.x;
    for (int v = tid; v < 12800; v += 256) {
        int q = v >> 8, k = v & 255;
        qvs[v] = qv[((size_t)q * 32 + b) * 256 + k];
    }
    __syncthreads();
    for (int p = tid; p < 2500; p += 256) {
        int q = p / 50, q2 = p % 50;
        float acc = 0.f;
        for (int k = 0; k < 256; k++) acc = fmaf(qvs[q * 256 + k], qvs[q2 * 256 + k], acc);
        G[((size_t)b * 50 + q) * 50 + q2] = acc;
    }
    if (tid < 52) {
        float s = 0.f;
        if (tid < 50) for (int k = 0; k < 256; k++) s += qvs[tid * 256 + k];
        qs[b * 52 + tid] = s;
    }
}

// ---- cvstats[b][t][2] = {sum, sumsq} over cv[t,b,:] ----
__global__ __launch_bounds__(256) void cvstats_prep(const float* __restrict__ cv,
                                                    float* __restrict__ st) {
    int blk = blockIdx.x;               // 9600
    int t = blk >> 5, b = blk & 31;
    int tid = threadIdx.x;
    float v = cv[((size_t)t * 32 + b) * 256 + tid];
    float s = v, s2 = v * v;
#pragma unroll
    for (int m = 32; m; m >>= 1) { s += __shfl_xor(s, m, 64); s2 += __shfl_xor(s2, m, 64); }
    __shared__ float red[8];
    if ((tid & 63) == 0) { red[(tid >> 6) * 2] = s; red[(tid >> 6) * 2 + 1] = s2; }
    __syncthreads();
    if (tid == 0) {
        float S = red[0] + red[2] + red[4] + red[6];
        float S2 = red[1] + red[3] + red[5] + red[7];
        st[((size_t)b * 300 + t) * 2] = S;
        st[((size_t)b * 300 + t) * 2 + 1] = S2;
    }
}

// ---- C12[dd][R][2] = {sum_k W[R,k]*gamma[k], sum_k W[R,k]*beta[k] + bih + bhh} ----
__global__ __launch_bounds__(256) void c1c2_prep(const float* __restrict__ Wih,
                                                 const float* __restrict__ lng,
                                                 const float* __restrict__ lnb,
                                                 const float* __restrict__ bih,
                                                 const float* __restrict__ bhh,
                                                 float* __restrict__ C12) {
    int id = blockIdx.x * 256 + threadIdx.x;    // < 2048
    int dd = id >> 10, R = id & 1023;
    float s1 = 0.f, s2 = 0.f;
    const float* wr = &Wih[((size_t)dd * 1024 + R) * 512];
    for (int k = 0; k < 512; k++) {
        float w = wr[k];
        s1 = fmaf(w, lng[dd * 512 + k], s1);
        s2 = fmaf(w, lnb[dd * 512 + k], s2);
    }
    C12[(size_t)id * 2] = s1;
    C12[(size_t)id * 2 + 1] = s2 + bih[dd * 1024 + R] + bhh[dd * 1024 + R];
}

// ================= main scan: 64 blocks; batched-retry seq-embedded exchange =================
__global__ __launch_bounds__(256, 1) void scan10(
    const int*   __restrict__ cmask,    // [32][300]
    const int*   __restrict__ qmask,    // [32][50]
    const float* __restrict__ Wgv,      // [2][256]
    const float* __restrict__ bgv,      // [2]
    const float* __restrict__ brp,      // [2][256]
    const u32*   __restrict__ Wtp,      // [2*32][40][128]
    const __half* __restrict__ whp,     // [2][32][50][256]
    const __half* __restrict__ hpp,     // [2][32][300][256]
    const __half* __restrict__ P1,      // [2*32][300][1024]
    const __half* __restrict__ VP,      // [2*32][1024][56]
    const float* __restrict__ C12,      // [2][1024][2]
    const float* __restrict__ G,        // [32][50][50]
    const float* __restrict__ qsr,      // [32][52]
    const float* __restrict__ cvst,     // [32][300][2]
    u64* __restrict__ HX,               // [2*32][128]  seq32|2f16
    u32* __restrict__ B2X,              // [2*32][1024] f32&~511|seq9
    u32* __restrict__ B3X,              // [2*32][256]  f32&~511|seq9
    float* __restrict__ out)            // [300][32][512]
{
    int blk = blockIdx.x;
    int dd = blk >> 5, j = blk & 31;
    int tid = threadIdx.x;
    int lane = tid & 63, wave = tid >> 6;
    int rr = lane & 31, kh = lane >> 5, sw = rr & 7;

    __shared__ __align__(16) u32 sh_wt[40 * 128];
    __shared__ __align__(16) u32 sh_x[32 * 128];
    __shared__ __align__(16) u32 sh_wh[6400];
    __shared__ float sh_G[50 * 50];
    __shared__ float sh_red[4 * 32 * 33];
    __shared__ float sh_red3[4 * 32 * 8];
    __shared__ float sh_a[256];
    __shared__ float sh_af[64];
    __shared__ __align__(16) u32 sh_al2[28];
    __shared__ float sh_alpha[64];
    __shared__ float sh_qb[64];
    __shared__ float sh_qs[52];
    __shared__ float sh_r2[4];
    __shared__ float sh_cs[2];
    __shared__ int   sh_len[32];

    // ---------- one-time staging ----------
    for (int v = tid; v < 40 * 128; v += 256) {
        int rl = v >> 7, u = v & 127;
        int c4 = u >> 2, w = u & 3;
        sh_wt[rl * 128 + (((c4 ^ (rl & 7)) << 2) | w)] =
            Wtp[((size_t)(dd * 32 + j) * 40 + rl) * 128 + u];
    }
    {
        const u32* whsrc = (const u32*)(whp + (size_t)(dd * 32 + j) * QL * H);
        for (int i = tid; i < 6400; i += 256) sh_wh[i] = whsrc[i];
    }
    for (int v = tid; v < 2500; v += 256) sh_G[v] = G[(size_t)j * 2500 + v];
    if (tid < 52) sh_qs[tid] = qsr[j * 52 + tid];
    if (tid < 64) sh_qb[tid] = (tid < QL) ? (qmask[j * QL + tid] ? 0.f : -1e30f) : -1e30f;
    if (tid < 32) sh_len[tid] = 0;
    __syncthreads();
    {
        int b = tid & 31, part = tid >> 5;
        int t0 = part * 38, t1 = t0 + 38 > PL ? PL : t0 + 38;
        int s = 0;
        for (int tt = t0; tt < t1; tt++) s += cmask[b * PL + tt];
        atomicAdd(&sh_len[b], s);
    }
    __syncthreads();

    float wgr[4];
#pragma unroll
    for (int i = 0; i < 4; i++) wgr[i] = Wgv[dd * H + lane + 64 * i];
    float bgs = bgv[dd];
    float brv = brp[dd * H + tid];
    float C1r[4], C2r[4];
#pragma unroll
    for (int k = 0; k < 4; k++) {
        C1r[k] = C12[((size_t)dd * 1024 + k * 256 + tid) * 2];
        C2r[k] = C12[((size_t)dd * 1024 + k * 256 + tid) * 2 + 1];
    }
    int len_j = sh_len[j];
    float c_reg = 0.f;

    // zero own-batch masked tail
    for (int t = len_j; t < PL; t++)
        out[((size_t)t * B + j) * 512 + dd * 256 + tid] = 0.f;

    // prologue: publish h(0)=0 with seq 1
    if (tid < 128) a_st64(HX + (size_t)(dd * 32 + j) * 128 + tid, ((u64)1 << 32));

    const __half* hpb = hpp + (size_t)(dd * 32 + j) * PL * H;
    const u32* VPu = (const u32*)VP;
    const u32* xrow  = sh_x + rr * 128;
    const u32* wrow  = sh_wt + rr * 128;
    const u32* wrow2 = sh_wt + (8 + rr) * 128;

    for (int t = 0; t < PL; t++) {
        u32 want = (u32)(t + 1);
        u32 want9 = want & 511;
        int tsj = dd ? (t < len_j ? len_j - 1 - t : t) : t;
        __syncthreads();   // protect sh_x / sh_a / sh_cs from prev-step stragglers

        // ---- A: own-batch loads (off critical path): P1 rows, hp, cv stats ----
        float p1v[4];
#pragma unroll
        for (int k = 0; k < 4; k++)
            p1v[k] = __half2float(P1[((size_t)(dd * 32 + j) * PL + tsj) * 1024 + k * 256 + tid]);
        float hpv = __half2float(hpb[(size_t)tsj * H + tid]);
        if (tid == 0) {
            sh_cs[0] = cvst[((size_t)j * 300 + tsj) * 2];
            sh_cs[1] = cvst[((size_t)j * 300 + tsj) * 2 + 1];
        }

        // ---- B: batched h poll (16 u64, independent loads per retry) + stage ----
        {
            const u64* base = HX + (size_t)dd * 32 * 128;
            u64 v[16];
            for (;;) {
                bool ok = true;
#pragma unroll
                for (int m = 0; m < 16; m++) v[m] = a_ld64(base + m * 256 + tid);
#pragma unroll
                for (int m = 0; m < 16; m++) ok &= ((u32)(v[m] >> 32) == want);
                if (ok) break;
                __builtin_amdgcn_s_sleep(2);
            }
#pragma unroll
            for (int m = 0; m < 16; m++) {
                int w = m * 256 + tid;
                int b = w >> 7, c2 = w & 127;
                sh_x[b * 128 + (((c2 >> 2) ^ (b & 7)) << 2) + (c2 & 3)] = (u32)v[m];
            }
        }
        __syncthreads();

        // ---- C: MFMA over h (K=256 split over 4 waves): gates (acc1) + Wr (acc2) ----
        {
            f32x16 acc1 = {}, acc2 = {};
#pragma unroll
            for (int kk = 0; kk < 4; kk++) {
                int c4 = wave * 8 + 2 * kk + kh;
                int pc4 = (c4 ^ sw) << 2;
                uint4 au = *(const uint4*)(xrow + pc4);
                uint4 b1 = *(const uint4*)(wrow + pc4);
                uint4 b2 = *(const uint4*)(wrow2 + pc4);
                acc1 = mfma16(au, b1, acc1);
                acc2 = mfma16(au, b2, acc2);
            }
#pragma unroll
            for (int q = 0; q < 16; q++) {
                int b = (q & 3) + 8 * (q >> 2) + 4 * kh;
                sh_red[(wave * 32 + b) * 33 + rr] = acc1[q];
            }
            if (rr >= 24) {
#pragma unroll
                for (int q = 0; q < 16; q++) {
                    int b = (q & 3) + 8 * (q >> 2) + 4 * kh;
                    sh_red3[(wave * 32 + b) * 8 + (rr - 24)] = acc2[q];
                }
            }
        }
        __syncthreads();

        // ---- D: reduce + publish B2 (4) / B3 (1) with seq9 in mantissa LSBs ----
        {
            int bb = tid >> 3, rq = (tid & 7) * 4;
            u32* dst = B2X + (size_t)(dd * 32 + bb) * 1024 + j * 32 + rq;
#pragma unroll
            for (int i = 0; i < 4; i++) {
                float f = sh_red[(0 * 32 + bb) * 33 + rq + i] + sh_red[(1 * 32 + bb) * 33 + rq + i]
                        + sh_red[(2 * 32 + bb) * 33 + rq + i] + sh_red[(3 * 32 + bb) * 33 + rq + i];
                a_st32(dst + i, (__builtin_bit_cast(u32, f) & ~511u) | want9);
            }
            int rw = tid & 7;
            float b3 = sh_red3[bb * 8 + rw] + sh_red3[(32 + bb) * 8 + rw]
                     + sh_red3[(64 + bb) * 8 + rw] + sh_red3[(96 + bb) * 8 + rw];
            a_st32(B3X + (size_t)(dd * 32 + bb) * 256 + 8 * j + rw,
                   (__builtin_bit_cast(u32, b3) & ~511u) | want9);
        }

        // ---- E: VP loads (own-batch alpha-VP weights, cached path) ----
        uint4 vp[28];
#pragma unroll
        for (int k = 0; k < 4; k++) {
            const uint4* vr = (const uint4*)(VPu + ((size_t)(dd * 32 + j) * 1024 + k * 256 + tid) * 28);
#pragma unroll
            for (int i = 0; i < 7; i++) vp[k * 7 + i] = vr[i];
        }

        // ---- F: batched B poll (5 independent words per retry) ----
        float bg2[4], hrv;
        {
            const u32* b2b = B2X + (size_t)(dd * 32 + j) * 1024 + (tid >> 3) * 32 + (tid & 7);
            const u32* b3b = B3X + (size_t)(dd * 32 + j) * 256 + tid;
            u32 v0, v1, v2, v3, v4;
            for (;;) {
                v0 = a_ld32(b2b);
                v1 = a_ld32(b2b + 8);
                v2 = a_ld32(b2b + 16);
                v3 = a_ld32(b2b + 24);
                v4 = a_ld32(b3b);
                bool ok = ((v0 & 511) == want9) & ((v1 & 511) == want9)
                        & ((v2 & 511) == want9) & ((v3 & 511) == want9)
                        & ((v4 & 511) == want9);
                if (ok) break;
                __builtin_amdgcn_s_sleep(2);
            }
            bg2[0] = __builtin_bit_cast(float, v0 & ~511u);
            bg2[1] = __builtin_bit_cast(float, v1 & ~511u);
            bg2[2] = __builtin_bit_cast(float, v2 & ~511u);
            bg2[3] = __builtin_bit_cast(float, v3 & ~511u);
            hrv    = __builtin_bit_cast(float, v4 & ~511u);
            sh_a[tid] = hrv + brv + hpv;
        }
        __syncthreads();

        // ---- G: attention logits ----
        {
            float av[4];
#pragma unroll
            for (int i = 0; i < 4; i++) av[i] = sh_a[lane + 64 * i];
            const __half* wh16 = (const __half*)sh_wh;
            for (int q = wave; q < QL; q += 4) {
                float a = 0.f;
#pragma unroll
                for (int i = 0; i < 4; i++) {
                    float xx = (float)wh16[q * 256 + lane + 64 * i] + av[i];
                    float e = __expf(2.f * xx);
                    a = fmaf(wgr[i], (e - 1.f) / (e + 1.f), a);
                }
#pragma unroll
                for (int m = 32; m; m >>= 1) a += __shfl_xor(a, m, 64);
                if (lane == 0) sh_alpha[q] = a + bgs + sh_qb[q];
            }
        }
        __syncthreads();

        // ---- H: softmax (wave 0) ----
        if (wave == 0) {
            float v = (lane < QL) ? sh_alpha[lane] : -1e30f;
            float m = v;
#pragma unroll
            for (int s = 32; s; s >>= 1) m = fmaxf(m, __shfl_xor(m, s, 64));
            float e = (lane < QL) ? __expf(v - m) : 0.f;
            float sum = e;
#pragma unroll
            for (int s = 32; s; s >>= 1) sum += __shfl_xor(sum, s, 64);
            float al = (lane < QL) ? e / sum : 0.f;
            sh_af[lane] = al;
            float alo = __shfl_xor(al, 1, 64);
            if (!(lane & 1) && lane < 56) sh_al2[lane >> 1] = packh2(al, alo);
        }
        __syncthreads();

        // ---- I: LN stats from Gram ----
        if (wave == 0) {
            float gd = 0.f;
            if (lane < QL) {
                const float* Grow = sh_G + lane * 50;
                float aq = sh_af[lane];
                for (int q2 = 0; q2 < QL; q2++) gd = fmaf(Grow[q2], sh_af[q2], gd);
                gd *= aq;
            }
#pragma unroll
            for (int m = 32; m; m >>= 1) gd += __shfl_xor(gd, m, 64);
            if (lane == 0) sh_r2[0] = gd;
        } else if (wave == 1) {
            float s = (lane < QL) ? sh_af[lane] * sh_qs[lane] : 0.f;
#pragma unroll
            for (int m = 32; m; m >>= 1) s += __shfl_xor(s, m, 64);
            if (lane == 0) sh_r2[1] = s;
        }
        __syncthreads();

        // ---- J: alpha . VP ----
        float aVP[4];
#pragma unroll
        for (int k = 0; k < 4; k++) {
            float acc = 0.f;
#pragma unroll
            for (int i = 0; i < 7; i++) {
                acc = fdot2(vp[k * 7 + i].x, sh_al2[i * 4 + 0], acc);
                acc = fdot2(vp[k * 7 + i].y, sh_al2[i * 4 + 1], acc);
                acc = fdot2(vp[k * 7 + i].z, sh_al2[i * 4 + 2], acc);
                acc = fdot2(vp[k * 7 + i].w, sh_al2[i * 4 + 3], acc);
            }
            aVP[k] = acc;
        }

        // ---- K: gates + LSTM pointwise + publish h(t+1) ----
        float hv;
        {
            float mu = (sh_cs[0] + sh_r2[1]) * (1.f / 512.f);
            float E2 = (sh_cs[1] + sh_r2[0]) * (1.f / 512.f);
            float rs = rsqrtf(E2 - mu * mu + 1e-5f);
            float gk[4];
#pragma unroll
            for (int k = 0; k < 4; k++)
                gk[k] = rs * (p1v[k] + aVP[k]) - rs * mu * C1r[k] + C2r[k] + bg2[k];
            float si = 1.f / (1.f + __expf(-gk[0]));
            float sf = 1.f / (1.f + __expf(-gk[1]));
            float so = 1.f / (1.f + __expf(-gk[3]));
            float eg = __expf(2.f * gk[2]); float tg = (eg - 1.f) / (eg + 1.f);
            float c = sf * c_reg + si * tg;
            float ec = __expf(2.f * c); float tc = (ec - 1.f) / (ec + 1.f);
            hv = so * tc;
            c_reg = c;
            float ho = __shfl_xor(hv, 1, 64);
            if (!(tid & 1))
                a_st64(HX + (size_t)(dd * 32 + j) * 128 + (tid >> 1),
                       (((u64)(t + 2)) << 32) | (u64)packh2(hv, ho));
        }

        // ---- L: output store ----
        if (t < len_j)
            out[((size_t)tsj * B + j) * 512 + dd * 256 + tid] = hv;
    }
}

extern "C" void kernel_launch(void* const* d_in, const int* in_sizes, int n_in,
                              void* d_out, int out_size, void* d_ws, size_t ws_size,
                              hipStream_t stream) {
    const float* cv    = (const float*)d_in[0];
    const int*   cmask = (const int*)  d_in[1];
    const float* qv    = (const float*)d_in[2];
    const int*   qmask = (const int*)  d_in[3];
    const float* Wq    = (const float*)d_in[4];
    const float* bq    = (const float*)d_in[5];
    const float* Wp    = (const float*)d_in[6];
    const float* bp    = (const float*)d_in[7];
    const float* Wr    = (const float*)d_in[8];
    const float* br    = (const float*)d_in[9];
    const float* Wg    = (const float*)d_in[10];
    const float* bg    = (const float*)d_in[11];
    const float* ln_g  = (const float*)d_in[12];
    const float* ln_b  = (const float*)d_in[13];
    const float* Wih   = (const float*)d_in[14];
    const float* Whh   = (const float*)d_in[15];
    const float* b_ih  = (const float*)d_in[16];
    const float* b_hh  = (const float*)d_in[17];
    float* out = (float*)d_out;

    uint8_t* ws = (uint8_t*)d_ws;
    u32*    Wtp = (u32*)ws;      ws += (size_t)2 * 32 * 40 * 128 * 4;   // 1.31 MB
    __half* VP  = (__half*)ws;   ws += (size_t)2 * 32 * 1024 * 56 * 2;  // 7.34 MB
    __half* whp = (__half*)ws;   ws += (size_t)2 * 32 * 50 * 256 * 2;   // 1.64 MB
    __half* hpp = (__half*)ws;   ws += (size_t)2 * 32 * 300 * 256 * 2;  // 9.83 MB
    __half* P1  = (__half*)ws;   ws += (size_t)2 * 32 * 300 * 1024 * 2; // 39.32 MB
    float*  C12 = (float*)ws;    ws += (size_t)2 * 1024 * 2 * 4;        // 16 KB
    float*  G   = (float*)ws;    ws += (size_t)32 * 50 * 50 * 4;        // 320 KB
    float*  qs  = (float*)ws;    ws += (size_t)32 * 52 * 4;             // 6.7 KB
    float*  cvs = (float*)ws;    ws += (size_t)32 * 300 * 2 * 4;        // 77 KB
    u64* HX  = (u64*)ws;         ws += (size_t)2 * 32 * 128 * 8;        // 64 KB
    u32* B2X = (u32*)ws;         ws += (size_t)2 * 32 * 1024 * 4;       // 256 KB
    u32* B3X = (u32*)ws;         ws += (size_t)2 * 32 * 256 * 4;        // 64 KB

    hipMemsetAsync(HX, 0, (size_t)2 * 32 * 128 * 8 + (size_t)2 * 32 * 1024 * 4
                          + (size_t)2 * 32 * 256 * 4, stream);
    hipLaunchKernelGGL(pack_wt2, dim3(1280), dim3(256), 0, stream, Whh, Wr, Wtp);
    hipLaunchKernelGGL(prep_proj, dim3(2 * 32 * 7), dim3(256), 0, stream,
                       qv, Wq, bq, whp, QL, 7);
    hipLaunchKernelGGL(prep_proj, dim3(2 * 32 * 38), dim3(256), 0, stream,
                       cv, Wp, bp, hpp, PL, 38);
    hipLaunchKernelGGL(p1_prep, dim3(2 * 32 * 38), dim3(256), 0, stream,
                       cv, Wih, ln_g, P1);
    hipLaunchKernelGGL(vp_prep, dim3(512), dim3(256), 0, stream, qv, Wih, ln_g, VP);
    hipLaunchKernelGGL(gram_prep, dim3(32), dim3(256), 0, stream, qv, G, qs);
    hipLaunchKernelGGL(cvstats_prep, dim3(9600), dim3(256), 0, stream, cv, cvs);
    hipLaunchKernelGGL(c1c2_prep, dim3(8), dim3(256), 0, stream,
                       Wih, ln_g, ln_b, b_ih, b_hh, C12);
    hipLaunchKernelGGL(scan10, dim3(64), dim3(256), 0, stream,
                       cmask, qmask, Wg, bg, br, Wtp, whp, hpp, P1, VP, C12, G, qs, cvs,
                       HX, B2X, B3X, out);
}